// Round 7
// baseline (97.216 us; speedup 1.0000x reference)
//
#include <hip/hip_runtime.h>
#include <cstdint>

// y[m][n] = sum_k x[m][k] * (q[n][k] * scale[n]) + bias[n]
// M=32, K=8192, N=8192; q = signed int4 nibbles packed 8 per int32.
// Harness dtype reality (verified round 4): fp16 tensors are FLOAT32 on
// device (inputs and output); b_packed is int32. ws_size ~268 MB.
// Harness fixed tax ~62 us (268 MB ws poison + restores); kernel budget is
// dur_us - 62.
#define M_DIM 32
#define K_DIM 8192
#define N_DIM 8192

typedef _Float16 f16x8 __attribute__((ext_vector_type(8)));
typedef _Float16 f16x2 __attribute__((ext_vector_type(2)));
typedef float    f32x4 __attribute__((ext_vector_type(4)));

__device__ __forceinline__ uint32_t u4e(uint4 v, int t) {
  return (t == 0) ? v.x : (t == 1) ? v.y : (t == 2) ? v.z : v.w;
}

// Magic-bias dequant: dword (8 nibbles) -> 8 exact f16 in [-8,7].
// Fragment element j holds nibble kp[j] = (j>>1)+(j&1)*4; xprep bakes the
// same permutation into A, so the MFMA dot product is exact.
__device__ __forceinline__ f16x8 dq8(uint32_t w) {
  union { uint32_t u[4]; f16x8 v; } r;
  const uint32_t MASK  = 0x000F000Fu;
  const uint32_t MAGIC = 0x64086408u;                 // f16x2 {1032, 1032}
  const f16x2 magic = __builtin_bit_cast(f16x2, MAGIC);
#pragma unroll
  for (int s = 0; s < 4; ++s) {
    uint32_t t = ((w >> (4 * s)) & MASK) ^ MAGIC;
    f16x2 h = __builtin_bit_cast(f16x2, t) - magic;
    r.u[s] = __builtin_bit_cast(uint32_t, h);
  }
  return r.v;
}

// -------- x prep: f32 x[32][8192] -> f16 xp[g=k/8][m][8], nibble-pair perm --
__global__ __launch_bounds__(256) void xprep_kernel(
    const float* __restrict__ x, uint4* __restrict__ xp) {
  const int T = blockIdx.x * 256 + threadIdx.x;  // 0..32767
  const int m = T >> 10;                         // 0..31
  const int g = T & 1023;                        // 0..1023
  const f32x4* p = (const f32x4*)(x + (size_t)m * K_DIM + (size_t)g * 8);
  f32x4 lo = p[0], hi = p[1];
  union { uint4 q; f16x8 v; } o;
#pragma unroll
  for (int s = 0; s < 4; ++s) {
    o.v[2 * s]     = (_Float16)lo[s];
    o.v[2 * s + 1] = (_Float16)hi[s];
  }
  xp[(size_t)g * 32 + m] = o.q;
}

// -------- main GEMM: 256 WGs x 1024 thr (16 waves) -------------------------
// Round-7 change: B is staged through LDS with PERFECTLY LINEAR global loads
// (a WG's 32 rows are one contiguous 128 KB block) instead of per-lane
// 4KB-strided scatter — tests/fixes the HBM channel-conflict hypothesis.
// Two 64 KB halves (rows 0-15, 16-31), padded row stride 4112 B.
// After fragment pickup the main loop is identical to round 6.
#define STRIDE_DW 1028                   // 4112 B rows: 16B-aligned, bank +4
__global__ __launch_bounds__(1024, 4) void qgemm_xp(
    const uint32_t* __restrict__ bq,     // packed int4 [N, K/8]
    const uint4*    __restrict__ xp,     // f16 [1024][32][8] (perm'd)
    const float*    __restrict__ sc,     // f32 [8192]
    const float*    __restrict__ bi,     // f32 [8192]
    float*          __restrict__ out) {  // f32 [32, 8192]
  __shared__ float    red[16][32][33];   // 66 KB  (epilogue reduce)
  __shared__ uint32_t stage[16 * STRIDE_DW];  // 64.25 KB (B half-stage)

  const int tid  = threadIdx.x;
  const int w    = tid >> 6;             // wave 0..15 -> k0 = w*512
  const int lane = tid & 63;
  const int l16  = lane & 15;
  const int quad = lane >> 4;
  const int n0   = blockIdx.x << 5;      // 32 n per WG

  // ---- B staging: WG block = uint4 [n0*256, n0*256 + 8192), fully linear.
  const uint4* bsrc = (const uint4*)bq + (size_t)n0 * 256;
  uint4 r0[4], r1[4];
#pragma unroll
  for (int i = 0; i < 4; ++i) r0[i] = bsrc[i * 1024 + tid];         // rows 0-15
#pragma unroll
  for (int i = 0; i < 4; ++i) r1[i] = bsrc[4096 + i * 1024 + tid];  // rows 16-31

  // A pointer (unchanged): uint4 index g*32 + m; g = w*64 + quad*4 + c*16 + t
  const uint4* ap = xp + (size_t)(((w << 6) + (quad << 2)) * 32 + l16);

  // half 0: write rows 0-15, pick up b0 fragments (row l16)
#pragma unroll
  for (int i = 0; i < 4; ++i) {
    const int gi  = i * 1024 + tid;
    const int row = gi >> 8, col4 = gi & 255;
    *(uint4*)&stage[row * STRIDE_DW + col4 * 4] = r0[i];
  }
  __syncthreads();
  uint4 b0[4], b1[4];
#pragma unroll
  for (int c = 0; c < 4; ++c)
    b0[c] = *(const uint4*)&stage[l16 * STRIDE_DW + ((w << 4) + (c << 2) + quad) * 4];
  __syncthreads();                       // all half-0 reads done before overwrite

  // half 1: rows 16-31, pick up b1 fragments (row 16+l16 -> stage row l16)
#pragma unroll
  for (int i = 0; i < 4; ++i) {
    const int gi  = i * 1024 + tid;
    const int row = gi >> 8, col4 = gi & 255;
    *(uint4*)&stage[row * STRIDE_DW + col4 * 4] = r1[i];
  }
  __syncthreads();
#pragma unroll
  for (int c = 0; c < 4; ++c)
    b1[c] = *(const uint4*)&stage[l16 * STRIDE_DW + ((w << 4) + (c << 2) + quad) * 4];

  // ---- main loop: identical to round 6 (A ping-pong, magic dequant, MFMA).
  f32x4 acc00 = {0.f, 0.f, 0.f, 0.f};
  f32x4 acc01 = {0.f, 0.f, 0.f, 0.f};
  f32x4 acc10 = {0.f, 0.f, 0.f, 0.f};
  f32x4 acc11 = {0.f, 0.f, 0.f, 0.f};

  uint4 a0c = ap[0], a1c = ap[16];       // group 0, both m-tiles
#pragma unroll
  for (int g = 0; g < 16; ++g) {
    const int gn  = (g + 1) & 15;        // last iter refetches group 0 (harmless)
    const int off = (((gn >> 2) * 16) + (gn & 3)) * 32;
    uint4 a0n = ap[off];
    uint4 a1n = ap[off + 16];

    const int c = g >> 2, t = g & 3;
    f16x8 fb0 = dq8(u4e(b0[c], t));
    f16x8 fb1 = dq8(u4e(b1[c], t));
    f16x8 fa0 = __builtin_bit_cast(f16x8, a0c);
    f16x8 fa1 = __builtin_bit_cast(f16x8, a1c);
    acc00 = __builtin_amdgcn_mfma_f32_16x16x32_f16(fa0, fb0, acc00, 0, 0, 0);
    acc01 = __builtin_amdgcn_mfma_f32_16x16x32_f16(fa1, fb0, acc01, 0, 0, 0);
    acc10 = __builtin_amdgcn_mfma_f32_16x16x32_f16(fa0, fb1, acc10, 0, 0, 0);
    acc11 = __builtin_amdgcn_mfma_f32_16x16x32_f16(fa1, fb1, acc11, 0, 0, 0);

    a0c = a0n; a1c = a1n;
  }

  // C/D layout (verified round 4): n = lane&15, m = quad*4 + r.
#pragma unroll
  for (int r = 0; r < 4; ++r) {
    const int mr = (quad << 2) + r;
    red[w][l16][mr]           = acc00[r];
    red[w][l16][mr + 16]      = acc01[r];
    red[w][l16 + 16][mr]      = acc10[r];
    red[w][l16 + 16][mr + 16] = acc11[r];
  }

  __syncthreads();

  // 1024 threads = one output each: n = tid&31, m = tid>>5.
  const int n = tid & 31;
  const int m = tid >> 5;
  float s = 0.f;
#pragma unroll
  for (int ww = 0; ww < 16; ++ww) s += red[ww][n][m];
  const int gnn = n0 + n;
  out[(size_t)m * N_DIM + gnn] = fmaf(s, sc[gnn], bi[gnn]);
}

// -------- fallback (tiny ws): round-4 known-good direct kernel -------------
__global__ __launch_bounds__(512) void qgemm_direct(
    const uint32_t* __restrict__ bq, const float* __restrict__ x,
    const float* __restrict__ sc, const float* __restrict__ bi,
    float* __restrict__ out) {
  __shared__ float red[8][32][40];
  const int tid  = threadIdx.x;
  const int w    = tid >> 6;
  const int lane = tid & 63;
  const int l16  = lane & 15;
  const int quad = lane >> 4;
  const int n0   = blockIdx.x << 5;

  const uint4* bq4 = (const uint4*)bq;
  const uint4* bp0 = bq4 + (size_t)(n0 + l16) * 256 + (w << 5) + quad;
  const uint4* bp1 = bp0 + (size_t)16 * 256;
  const float* ap0 = x + (size_t)l16 * K_DIM + (w << 10) + (quad << 5);
  const float* ap1 = ap0 + (size_t)16 * K_DIM;

  f32x4 acc00 = {0.f,0.f,0.f,0.f}, acc01 = {0.f,0.f,0.f,0.f};
  f32x4 acc10 = {0.f,0.f,0.f,0.f}, acc11 = {0.f,0.f,0.f,0.f};
#pragma unroll
  for (int c = 0; c < 8; ++c) {
    const uint4 wb0 = bp0[c * 4];
    const uint4 wb1 = bp1[c * 4];
#pragma unroll
    for (int t = 0; t < 4; ++t) {
      const float* a0 = ap0 + c * 128 + t * 8;
      const float* a1 = ap1 + c * 128 + t * 8;
      f32x4 l0 = *(const f32x4*)a0, h0 = *(const f32x4*)(a0 + 4);
      f32x4 l1 = *(const f32x4*)a1, h1 = *(const f32x4*)(a1 + 4);
      f16x8 fa0, fa1;
#pragma unroll
      for (int s = 0; s < 4; ++s) {
        fa0[2*s] = (_Float16)l0[s]; fa0[2*s+1] = (_Float16)h0[s];
        fa1[2*s] = (_Float16)l1[s]; fa1[2*s+1] = (_Float16)h1[s];
      }
      f16x8 fb0 = dq8(u4e(wb0, t));
      f16x8 fb1 = dq8(u4e(wb1, t));
      acc00 = __builtin_amdgcn_mfma_f32_16x16x32_f16(fa0, fb0, acc00, 0, 0, 0);
      acc01 = __builtin_amdgcn_mfma_f32_16x16x32_f16(fa1, fb0, acc01, 0, 0, 0);
      acc10 = __builtin_amdgcn_mfma_f32_16x16x32_f16(fa0, fb1, acc10, 0, 0, 0);
      acc11 = __builtin_amdgcn_mfma_f32_16x16x32_f16(fa1, fb1, acc11, 0, 0, 0);
    }
  }
#pragma unroll
  for (int r = 0; r < 4; ++r) {
    const int mr = (quad << 2) + r;
    red[w][l16][mr]           = acc00[r];
    red[w][l16][mr + 16]      = acc01[r];
    red[w][l16 + 16][mr]      = acc10[r];
    red[w][l16 + 16][mr + 16] = acc11[r];
  }
  __syncthreads();
  const int n  = tid & 31;
  const int mh = tid >> 5;
  float s0 = 0.f, s1 = 0.f;
#pragma unroll
  for (int ww = 0; ww < 8; ++ww) { s0 += red[ww][n][mh]; s1 += red[ww][n][mh+16]; }
  const int gn = n0 + n;
  out[(size_t)mh * N_DIM + gn]        = fmaf(s0, sc[gn], bi[gn]);
  out[(size_t)(mh + 16) * N_DIM + gn] = fmaf(s1, sc[gn], bi[gn]);
}

extern "C" void kernel_launch(void* const* d_in, const int* in_sizes, int n_in,
                              void* d_out, int out_size, void* d_ws, size_t ws_size,
                              hipStream_t stream) {
  const float*    x  = (const float*)d_in[0];     // f32 [32,8192]
  const uint32_t* bq = (const uint32_t*)d_in[1];  // int32 [8192,1024]
  const float*    sc = (const float*)d_in[2];     // f32 [8192]
  const float*    bi = (const float*)d_in[3];     // f32 [8192]
  float*          y  = (float*)d_out;             // f32 [32,8192]

  const size_t XP_BYTES = (size_t)M_DIM * K_DIM * 2;  // 512 KB f16
  if (ws_size >= XP_BYTES) {                          // constant -> graph-safe
    uint4* xp = (uint4*)d_ws;
    xprep_kernel<<<128, 256, 0, stream>>>(x, xp);
    qgemm_xp<<<N_DIM / 32, 1024, 0, stream>>>(bq, xp, sc, bi, y);
  } else {
    qgemm_direct<<<N_DIM / 32, 512, 0, stream>>>(bq, x, sc, bi, y);
  }
}

// Round 8
// 91.270 us; speedup vs baseline: 1.0652x; 1.0652x over previous
//
#include <hip/hip_runtime.h>
#include <cstdint>

// y[m][n] = sum_k x[m][k] * (q[n][k] * scale[n]) + bias[n]
// M=32, K=8192, N=8192; q = signed int4 nibbles packed 8 per int32.
// Harness dtype reality (verified round 4): fp16 tensors are FLOAT32 on
// device (inputs and output); b_packed is int32. ws_size ~268 MB.
// Fixed harness tax ~62 us (ws poison + restores); kernel budget = dur - 62.
#define M_DIM 32
#define K_DIM 8192
#define N_DIM 8192
#define MN    (M_DIM * N_DIM)

typedef _Float16 f16x8 __attribute__((ext_vector_type(8)));
typedef _Float16 f16x2 __attribute__((ext_vector_type(2)));
typedef float    f32x4 __attribute__((ext_vector_type(4)));

__device__ __forceinline__ uint32_t u4e(uint4 v, int t) {
  return (t == 0) ? v.x : (t == 1) ? v.y : (t == 2) ? v.z : v.w;
}

// Magic-bias dequant: dword (8 nibbles) -> 8 exact f16 in [-8,7].
// Element j holds nibble kp[j] = (j>>1)+(j&1)*4; xprep bakes the same
// permutation into A, so the MFMA dot product is exact.
__device__ __forceinline__ f16x8 dq8(uint32_t w) {
  union { uint32_t u[4]; f16x8 v; } r;
  const uint32_t MASK  = 0x000F000Fu;
  const uint32_t MAGIC = 0x64086408u;                 // f16x2 {1032, 1032}
  const f16x2 magic = __builtin_bit_cast(f16x2, MAGIC);
#pragma unroll
  for (int s = 0; s < 4; ++s) {
    uint32_t t = ((w >> (4 * s)) & MASK) ^ MAGIC;
    f16x2 h = __builtin_bit_cast(f16x2, t) - magic;
    r.u[s] = __builtin_bit_cast(uint32_t, h);
  }
  return r.v;
}

// -------- x prep: f32 x[32][8192] -> f16 xp[d=k/8][m][8], nibble-pair perm --
__global__ __launch_bounds__(256) void xprep_kernel(
    const float* __restrict__ x, uint4* __restrict__ xp) {
  const int T = blockIdx.x * 256 + threadIdx.x;  // 0..32767
  const int m = T >> 10;                         // 0..31
  const int g = T & 1023;                        // 0..1023
  const f32x4* p = (const f32x4*)(x + (size_t)m * K_DIM + (size_t)g * 8);
  f32x4 lo = p[0], hi = p[1];
  union { uint4 q; f16x8 v; } o;
#pragma unroll
  for (int s = 0; s < 4; ++s) {
    o.v[2 * s]     = (_Float16)lo[s];
    o.v[2 * s + 1] = (_Float16)hi[s];
  }
  xp[(size_t)g * 32 + m] = o.q;
}

// -------- main GEMM: 512 WGs x 512 thr (8 waves), 2 WGs/CU -----------------
// WG = 64 n-cols x 2048 k (kq = k-quarter). 8 waves k-split 256 k each.
// Halves A(L3/L2) traffic vs round 6 (64 MB total) and doubles WGs/CU so one
// WG's B drain overlaps the other's compute. Writes f32 partials to ws;
// reduce_kernel folds the 4 k-quarters + scale/bias.
// k-map: slot (c,t,quad,j) of wave w takes
//   d = kq*256 + w*32 + c*16 + quad*4 + t,  k = d*8 + kp[j]
// from BOTH operands — same bijection, exact dot product.
__global__ __launch_bounds__(512, 4) void qgemm2(
    const uint32_t* __restrict__ bq,     // packed int4 [N, K/8]
    const uint4*    __restrict__ xp,     // f16 [1024][32][8] (perm'd)
    float*          __restrict__ part) { // f32 [4][32][8192] partials (ws)
  __shared__ float red[8][64][33];       // 67.6 KB -> 2 WGs/CU

  const int tid  = threadIdx.x;
  const int w    = tid >> 6;             // wave 0..7
  const int lane = tid & 63;
  const int l16  = lane & 15;
  const int quad = lane >> 4;
  const int ntile = blockIdx.x & 127;    // n-tile fastest -> XCD spread
  const int kq    = blockIdx.x >> 7;     // 0..3
  const int n0    = ntile << 6;          // 64 n per WG

  // B: 4 n-row-tiles x 2 uint4, all 8 loads issued upfront.
  // uint4 idx = row*256 + kq*64 + w*8 + c*4 + quad
  const uint4* bq4  = (const uint4*)bq;
  const int    cb   = (kq << 6) + (w << 3) + quad;
  uint4 b[4][2];
#pragma unroll
  for (int r = 0; r < 4; ++r)
#pragma unroll
    for (int c = 0; c < 2; ++c)
      b[r][c] = bq4[(size_t)(n0 + r * 16 + l16) * 256 + cb + c * 4];

  // A: d(step s) = dbase + (s>>2)*16 + (s&3); xp idx = d*32 + m
  const int dbase = (kq << 8) + (w << 5) + (quad << 2);
  uint4 am0[8], am1[8];
#pragma unroll
  for (int s = 0; s < 3; ++s) {          // 3-deep prefetch
    const int d = dbase + ((s >> 2) << 4) + (s & 3);
    am0[s] = xp[d * 32 + l16];
    am1[s] = xp[d * 32 + l16 + 16];
  }

  f32x4 acc[4][2];
#pragma unroll
  for (int r = 0; r < 4; ++r)
#pragma unroll
    for (int mt = 0; mt < 2; ++mt) acc[r][mt] = (f32x4){0.f, 0.f, 0.f, 0.f};

#pragma unroll
  for (int s = 0; s < 8; ++s) {          // 8 k-steps of 32
    if (s < 5) {
      const int sp = s + 3;
      const int d  = dbase + ((sp >> 2) << 4) + (sp & 3);
      am0[sp] = xp[d * 32 + l16];
      am1[sp] = xp[d * 32 + l16 + 16];
    }
    const int c = s >> 2, t = s & 3;
    f16x8 fa0 = __builtin_bit_cast(f16x8, am0[s]);
    f16x8 fa1 = __builtin_bit_cast(f16x8, am1[s]);
#pragma unroll
    for (int r = 0; r < 4; ++r) {
      f16x8 fb = dq8(u4e(b[r][c], t));
      acc[r][0] = __builtin_amdgcn_mfma_f32_16x16x32_f16(fa0, fb, acc[r][0], 0, 0, 0);
      acc[r][1] = __builtin_amdgcn_mfma_f32_16x16x32_f16(fa1, fb, acc[r][1], 0, 0, 0);
    }
  }

  // C/D layout (verified): n-col = r*16 + (lane&15), m = quad*4 + e (+16).
#pragma unroll
  for (int r = 0; r < 4; ++r)
#pragma unroll
    for (int mt = 0; mt < 2; ++mt)
#pragma unroll
      for (int e = 0; e < 4; ++e)
        red[w][r * 16 + l16][mt * 16 + (quad << 2) + e] = acc[r][mt][e];

  __syncthreads();

  // Cross-wave reduce: 2048 outputs / 512 threads = 4 each.
  const int n  = tid & 63;
  const int mb = tid >> 6;               // 0..7
  float* pp = part + (size_t)kq * MN;
#pragma unroll
  for (int i = 0; i < 4; ++i) {
    const int m = mb + (i << 3);
    float s = 0.f;
#pragma unroll
    for (int ww = 0; ww < 8; ++ww) s += red[ww][n][m];
    pp[(size_t)m * N_DIM + n0 + n] = s;
  }
}

// -------- fold 4 k-quarter partials + scale/bias ---------------------------
__global__ __launch_bounds__(256) void reduce_kernel(
    const float* __restrict__ part, const float* __restrict__ sc,
    const float* __restrict__ bi, float* __restrict__ out) {
  const int idx = blockIdx.x * 256 + threadIdx.x;   // 0..262143
  const int n = idx & (N_DIM - 1);
  float s = part[idx] + part[idx + MN] + part[idx + 2 * MN] + part[idx + 3 * MN];
  out[idx] = fmaf(s, sc[n], bi[n]);
}

// -------- fallback (tiny ws): round-4 known-good direct kernel -------------
__global__ __launch_bounds__(512) void qgemm_direct(
    const uint32_t* __restrict__ bq, const float* __restrict__ x,
    const float* __restrict__ sc, const float* __restrict__ bi,
    float* __restrict__ out) {
  __shared__ float red[8][32][40];
  const int tid  = threadIdx.x;
  const int w    = tid >> 6;
  const int lane = tid & 63;
  const int l16  = lane & 15;
  const int quad = lane >> 4;
  const int n0   = blockIdx.x << 5;

  const uint4* bq4 = (const uint4*)bq;
  const uint4* bp0 = bq4 + (size_t)(n0 + l16) * 256 + (w << 5) + quad;
  const uint4* bp1 = bp0 + (size_t)16 * 256;
  const float* ap0 = x + (size_t)l16 * K_DIM + (w << 10) + (quad << 5);
  const float* ap1 = ap0 + (size_t)16 * K_DIM;

  f32x4 acc00 = {0.f,0.f,0.f,0.f}, acc01 = {0.f,0.f,0.f,0.f};
  f32x4 acc10 = {0.f,0.f,0.f,0.f}, acc11 = {0.f,0.f,0.f,0.f};
#pragma unroll
  for (int c = 0; c < 8; ++c) {
    const uint4 wb0 = bp0[c * 4];
    const uint4 wb1 = bp1[c * 4];
#pragma unroll
    for (int t = 0; t < 4; ++t) {
      const float* a0 = ap0 + c * 128 + t * 8;
      const float* a1 = ap1 + c * 128 + t * 8;
      f32x4 l0 = *(const f32x4*)a0, h0 = *(const f32x4*)(a0 + 4);
      f32x4 l1 = *(const f32x4*)a1, h1 = *(const f32x4*)(a1 + 4);
      f16x8 fa0, fa1;
#pragma unroll
      for (int s = 0; s < 4; ++s) {
        fa0[2*s] = (_Float16)l0[s]; fa0[2*s+1] = (_Float16)h0[s];
        fa1[2*s] = (_Float16)l1[s]; fa1[2*s+1] = (_Float16)h1[s];
      }
      f16x8 fb0 = dq8(u4e(wb0, t));
      f16x8 fb1 = dq8(u4e(wb1, t));
      acc00 = __builtin_amdgcn_mfma_f32_16x16x32_f16(fa0, fb0, acc00, 0, 0, 0);
      acc01 = __builtin_amdgcn_mfma_f32_16x16x32_f16(fa1, fb0, acc01, 0, 0, 0);
      acc10 = __builtin_amdgcn_mfma_f32_16x16x32_f16(fa0, fb1, acc10, 0, 0, 0);
      acc11 = __builtin_amdgcn_mfma_f32_16x16x32_f16(fa1, fb1, acc11, 0, 0, 0);
    }
  }
#pragma unroll
  for (int r = 0; r < 4; ++r) {
    const int mr = (quad << 2) + r;
    red[w][l16][mr]           = acc00[r];
    red[w][l16][mr + 16]      = acc01[r];
    red[w][l16 + 16][mr]      = acc10[r];
    red[w][l16 + 16][mr + 16] = acc11[r];
  }
  __syncthreads();
  const int n  = tid & 31;
  const int mh = tid >> 5;
  float s0 = 0.f, s1 = 0.f;
#pragma unroll
  for (int ww = 0; ww < 8; ++ww) { s0 += red[ww][n][mh]; s1 += red[ww][n][mh+16]; }
  const int gn = n0 + n;
  out[(size_t)mh * N_DIM + gn]        = fmaf(s0, sc[gn], bi[gn]);
  out[(size_t)(mh + 16) * N_DIM + gn] = fmaf(s1, sc[gn], bi[gn]);
}

extern "C" void kernel_launch(void* const* d_in, const int* in_sizes, int n_in,
                              void* d_out, int out_size, void* d_ws, size_t ws_size,
                              hipStream_t stream) {
  const float*    x  = (const float*)d_in[0];     // f32 [32,8192]
  const uint32_t* bq = (const uint32_t*)d_in[1];  // int32 [8192,1024]
  const float*    sc = (const float*)d_in[2];     // f32 [8192]
  const float*    bi = (const float*)d_in[3];     // f32 [8192]
  float*          y  = (float*)d_out;             // f32 [32,8192]

  // ws layout: [0, 512K) xp f16; [1M, 5M) partials f32[4][32][8192]
  const size_t WS_NEED = (size_t)5 * (1 << 20) + (1 << 20);
  if (ws_size >= WS_NEED) {                       // constant -> graph-safe
    uint4* xp   = (uint4*)d_ws;
    float* part = (float*)((char*)d_ws + (1 << 20));
    xprep_kernel<<<128, 256, 0, stream>>>(x, xp);
    qgemm2<<<512, 512, 0, stream>>>(bq, xp, part);
    reduce_kernel<<<MN / 256, 256, 0, stream>>>(part, sc, bi, y);
  } else {
    qgemm_direct<<<N_DIM / 32, 512, 0, stream>>>(bq, x, sc, bi, y);
  }
}

// Round 9
// 90.816 us; speedup vs baseline: 1.0705x; 1.0050x over previous
//
#include <hip/hip_runtime.h>
#include <cstdint>

// y[m][n] = sum_k x[m][k] * (q[n][k] * scale[n]) + bias[n]
// M=32, K=8192, N=8192; int4 nibbles packed 8/int32.
// Verified: fp16 tensors are FLOAT32 on device (in & out); b_packed int32.
// Fixed harness tax ~62 us. Ledger: kernel time has been invariant (~20us)
// to VALU, VGPR, A-traffic, B-stride at 4 waves/SIMD; only waves/SIMD ever
// moved it (2->4 = 2.4x). Round 9 tests 8 waves/SIMD (latency-bound theory).
#define M_DIM 32
#define K_DIM 8192
#define N_DIM 8192
#define MN    (M_DIM * N_DIM)

typedef _Float16 f16x8 __attribute__((ext_vector_type(8)));
typedef _Float16 f16x2 __attribute__((ext_vector_type(2)));
typedef float    f32x4 __attribute__((ext_vector_type(4)));

__device__ __forceinline__ uint32_t u4e(uint4 v, int t) {
  return (t == 0) ? v.x : (t == 1) ? v.y : (t == 2) ? v.z : v.w;
}

// Magic-bias dequant: dword (8 nibbles) -> 8 exact f16 in [-8,7].
// Element j holds nibble kp[j] = (j>>1)+(j&1)*4; xprep bakes the same
// permutation into A, so the MFMA dot product is exact.
__device__ __forceinline__ f16x8 dq8(uint32_t w) {
  union { uint32_t u[4]; f16x8 v; } r;
  const uint32_t MASK  = 0x000F000Fu;
  const uint32_t MAGIC = 0x64086408u;                 // f16x2 {1032, 1032}
  const f16x2 magic = __builtin_bit_cast(f16x2, MAGIC);
#pragma unroll
  for (int s = 0; s < 4; ++s) {
    uint32_t t = ((w >> (4 * s)) & MASK) ^ MAGIC;
    f16x2 h = __builtin_bit_cast(f16x2, t) - magic;
    r.u[s] = __builtin_bit_cast(uint32_t, h);
  }
  return r.v;
}

// -------- x prep: f32 x[32][8192] -> f16 xp[d=k/8][m][8], nibble-pair perm --
__global__ __launch_bounds__(256) void xprep_kernel(
    const float* __restrict__ x, uint4* __restrict__ xp) {
  const int T = blockIdx.x * 256 + threadIdx.x;  // 0..32767
  const int m = T >> 10;                         // 0..31
  const int g = T & 1023;                        // 0..1023
  const f32x4* p = (const f32x4*)(x + (size_t)m * K_DIM + (size_t)g * 8);
  f32x4 lo = p[0], hi = p[1];
  union { uint4 q; f16x8 v; } o;
#pragma unroll
  for (int s = 0; s < 4; ++s) {
    o.v[2 * s]     = (_Float16)lo[s];
    o.v[2 * s + 1] = (_Float16)hi[s];
  }
  xp[(size_t)g * 32 + m] = o.q;
}

// -------- main GEMM: 512 WGs x 1024 thr, 2 WGs/CU = 8 waves/SIMD -----------
// WG = 32 n x 4096 k (kq = k-half); 16 waves x 256 k each.
// VGPR budget (launch_bounds 1024,8 -> 64): B 4xuint4(16) + A ping 4(16) +
// acc 4xf32x4(16) + addr ~12 = ~60.
// k-map: slot (c,t,quad,j) of wave w: d = kq*512 + w*32 + c*16 + quad*4 + t,
// k = d*8 + kp[j] — same bijection on A and B, exact dot product.
__global__ __launch_bounds__(1024, 8) void qgemm9(
    const uint32_t* __restrict__ bq,     // packed int4 [N, K/8]
    const uint4*    __restrict__ xp,     // f16 [1024][32][8] (perm'd)
    float*          __restrict__ part) { // f32 [2][32][8192] partials (ws)
  __shared__ float red[16][32][33];      // 67.6 KB -> 2 WGs/CU

  const int tid  = threadIdx.x;
  const int w    = tid >> 6;             // wave 0..15
  const int lane = tid & 63;
  const int l16  = lane & 15;
  const int quad = lane >> 4;
  const int ntile = blockIdx.x & 255;    // n-tile fastest -> XCD spread
  const int kq    = blockIdx.x >> 8;     // 0..1
  const int n0    = ntile << 5;          // 32 n per WG

  // B: rows n0+l16, n0+16+l16; uint4 idx = row*256 + kq*128 + w*8 + c*4 + quad
  const uint4* bq4 = (const uint4*)bq;
  const int    cb  = (kq << 7) + (w << 3) + quad;
  uint4 b[2][2];
#pragma unroll
  for (int r = 0; r < 2; ++r)
#pragma unroll
    for (int c = 0; c < 2; ++c)
      b[r][c] = bq4[(size_t)(n0 + r * 16 + l16) * 256 + cb + c * 4];

  // A: d(step s) = dbase + (s>>2)*16 + (s&3); xp idx = d*32 + m
  const int dbase = (kq << 9) + (w << 5) + (quad << 2);
  const uint4* ap = xp + (size_t)dbase * 32;

  f32x4 acc00 = {0.f, 0.f, 0.f, 0.f};   // ntile0 x mtile0
  f32x4 acc01 = {0.f, 0.f, 0.f, 0.f};   // ntile0 x mtile1
  f32x4 acc10 = {0.f, 0.f, 0.f, 0.f};   // ntile1 x mtile0
  f32x4 acc11 = {0.f, 0.f, 0.f, 0.f};   // ntile1 x mtile1

  uint4 a0c = ap[l16], a1c = ap[l16 + 16];   // step 0
#pragma unroll
  for (int s = 0; s < 8; ++s) {          // 8 k-steps of 32
    const int sn  = (s + 1) & 7;         // last iter refetches step 0 (harmless)
    const int off = (((sn >> 2) << 4) + (sn & 3)) * 32;
    uint4 a0n = ap[off + l16];
    uint4 a1n = ap[off + l16 + 16];

    const int c = s >> 2, t = s & 3;
    f16x8 fb0 = dq8(u4e(b[0][c], t));
    f16x8 fb1 = dq8(u4e(b[1][c], t));
    f16x8 fa0 = __builtin_bit_cast(f16x8, a0c);
    f16x8 fa1 = __builtin_bit_cast(f16x8, a1c);
    acc00 = __builtin_amdgcn_mfma_f32_16x16x32_f16(fa0, fb0, acc00, 0, 0, 0);
    acc01 = __builtin_amdgcn_mfma_f32_16x16x32_f16(fa1, fb0, acc01, 0, 0, 0);
    acc10 = __builtin_amdgcn_mfma_f32_16x16x32_f16(fa0, fb1, acc10, 0, 0, 0);
    acc11 = __builtin_amdgcn_mfma_f32_16x16x32_f16(fa1, fb1, acc11, 0, 0, 0);

    a0c = a0n; a1c = a1n;
  }

  // C/D layout (verified): n = r*16 + (lane&15), m = quad*4 + e (+16 mtile1).
#pragma unroll
  for (int e = 0; e < 4; ++e) {
    const int mr = (quad << 2) + e;
    red[w][l16][mr]           = acc00[e];
    red[w][l16][mr + 16]      = acc01[e];
    red[w][l16 + 16][mr]      = acc10[e];
    red[w][l16 + 16][mr + 16] = acc11[e];
  }

  __syncthreads();

  // 1024 outputs / 1024 threads: n = tid&31, m = tid>>5.
  const int n = tid & 31;
  const int m = tid >> 5;
  float s = 0.f;
#pragma unroll
  for (int ww = 0; ww < 16; ++ww) s += red[ww][n][m];
  part[(size_t)kq * MN + (size_t)m * N_DIM + n0 + n] = s;
}

// -------- fold 2 k-half partials + scale/bias ------------------------------
__global__ __launch_bounds__(256) void reduce_kernel(
    const float* __restrict__ part, const float* __restrict__ sc,
    const float* __restrict__ bi, float* __restrict__ out) {
  const int idx = blockIdx.x * 256 + threadIdx.x;   // 0..MN-1
  const int n = idx & (N_DIM - 1);
  float s = part[idx] + part[idx + MN];
  out[idx] = fmaf(s, sc[n], bi[n]);
}

// -------- fallback (tiny ws): round-4 known-good direct kernel -------------
__global__ __launch_bounds__(512) void qgemm_direct(
    const uint32_t* __restrict__ bq, const float* __restrict__ x,
    const float* __restrict__ sc, const float* __restrict__ bi,
    float* __restrict__ out) {
  __shared__ float red[8][32][40];
  const int tid  = threadIdx.x;
  const int w    = tid >> 6;
  const int lane = tid & 63;
  const int l16  = lane & 15;
  const int quad = lane >> 4;
  const int n0   = blockIdx.x << 5;

  const uint4* bq4 = (const uint4*)bq;
  const uint4* bp0 = bq4 + (size_t)(n0 + l16) * 256 + (w << 5) + quad;
  const uint4* bp1 = bp0 + (size_t)16 * 256;
  const float* ap0 = x + (size_t)l16 * K_DIM + (w << 10) + (quad << 5);
  const float* ap1 = ap0 + (size_t)16 * K_DIM;

  f32x4 acc00 = {0.f,0.f,0.f,0.f}, acc01 = {0.f,0.f,0.f,0.f};
  f32x4 acc10 = {0.f,0.f,0.f,0.f}, acc11 = {0.f,0.f,0.f,0.f};
#pragma unroll
  for (int c = 0; c < 8; ++c) {
    const uint4 wb0 = bp0[c * 4];
    const uint4 wb1 = bp1[c * 4];
#pragma unroll
    for (int t = 0; t < 4; ++t) {
      const float* a0 = ap0 + c * 128 + t * 8;
      const float* a1 = ap1 + c * 128 + t * 8;
      f32x4 l0 = *(const f32x4*)a0, h0 = *(const f32x4*)(a0 + 4);
      f32x4 l1 = *(const f32x4*)a1, h1 = *(const f32x4*)(a1 + 4);
      f16x8 fa0, fa1;
#pragma unroll
      for (int s = 0; s < 4; ++s) {
        fa0[2*s] = (_Float16)l0[s]; fa0[2*s+1] = (_Float16)h0[s];
        fa1[2*s] = (_Float16)l1[s]; fa1[2*s+1] = (_Float16)h1[s];
      }
      f16x8 fb0 = dq8(u4e(wb0, t));
      f16x8 fb1 = dq8(u4e(wb1, t));
      acc00 = __builtin_amdgcn_mfma_f32_16x16x32_f16(fa0, fb0, acc00, 0, 0, 0);
      acc01 = __builtin_amdgcn_mfma_f32_16x16x32_f16(fa1, fb0, acc01, 0, 0, 0);
      acc10 = __builtin_amdgcn_mfma_f32_16x16x32_f16(fa0, fb1, acc10, 0, 0, 0);
      acc11 = __builtin_amdgcn_mfma_f32_16x16x32_f16(fa1, fb1, acc11, 0, 0, 0);
    }
  }
#pragma unroll
  for (int r = 0; r < 4; ++r) {
    const int mr = (quad << 2) + r;
    red[w][l16][mr]           = acc00[r];
    red[w][l16][mr + 16]      = acc01[r];
    red[w][l16 + 16][mr]      = acc10[r];
    red[w][l16 + 16][mr + 16] = acc11[r];
  }
  __syncthreads();
  const int n  = tid & 31;
  const int mh = tid >> 5;
  float s0 = 0.f, s1 = 0.f;
#pragma unroll
  for (int ww = 0; ww < 8; ++ww) { s0 += red[ww][n][mh]; s1 += red[ww][n][mh+16]; }
  const int gn = n0 + n;
  out[(size_t)mh * N_DIM + gn]        = fmaf(s0, sc[gn], bi[gn]);
  out[(size_t)(mh + 16) * N_DIM + gn] = fmaf(s1, sc[gn], bi[gn]);
}

extern "C" void kernel_launch(void* const* d_in, const int* in_sizes, int n_in,
                              void* d_out, int out_size, void* d_ws, size_t ws_size,
                              hipStream_t stream) {
  const float*    x  = (const float*)d_in[0];     // f32 [32,8192]
  const uint32_t* bq = (const uint32_t*)d_in[1];  // int32 [8192,1024]
  const float*    sc = (const float*)d_in[2];     // f32 [8192]
  const float*    bi = (const float*)d_in[3];     // f32 [8192]
  float*          y  = (float*)d_out;             // f32 [32,8192]

  // ws layout: [0, 512K) xp f16; [1M, 3M) partials f32[2][32][8192]
  const size_t WS_NEED = (size_t)3 * (1 << 20);
  if (ws_size >= WS_NEED) {                       // constant -> graph-safe
    uint4* xp   = (uint4*)d_ws;
    float* part = (float*)((char*)d_ws + (1 << 20));
    xprep_kernel<<<128, 256, 0, stream>>>(x, xp);
    qgemm9<<<512, 1024, 0, stream>>>(bq, xp, part);
    reduce_kernel<<<MN / 256, 256, 0, stream>>>(part, sc, bi, y);
  } else {
    qgemm_direct<<<N_DIM / 32, 512, 0, stream>>>(bq, x, sc, bi, y);
  }
}